// Round 2
// baseline (662.083 us; speedup 1.0000x reference)
//
#include <hip/hip_runtime.h>
#include <hip/hip_bf16.h>

#define DD 128
#define HH 128
#define NATOMS 512
#define NK 1536   // 3*N
#define CHUNK 32  // atoms per forces block
#define NCHUNK (NATOMS / CHUNK)  // 16

// ---------------- Kernel 1: per-atom MLP forward + input gradient ----------------
__global__ __launch_bounds__(128) void mlp_grad_kernel(
    const float* __restrict__ desc,    // [N,D]
    const float* __restrict__ W0,      // [S,H,D]
    const float* __restrict__ b0,      // [S,H]
    const float* __restrict__ W1,      // [S,H,H]
    const float* __restrict__ b1,      // [S,H]
    const float* __restrict__ W2,      // [S,1,H]
    const float* __restrict__ b2,      // [S,1]
    const int*   __restrict__ species, // [N]
    float* __restrict__ G,             // ws [N,D]
    float* __restrict__ E)             // ws [N]
{
    const int i = blockIdx.x;
    const int t = threadIdx.x;
    __shared__ float s_desc[128];
    __shared__ float s_h0[128];
    __shared__ float s_d1[128];
    __shared__ float s_d0[128];
    __shared__ float s_red[2];

    const int sp = species[i];
    const float* w0 = W0 + sp * 128 * 128;
    const float* w1 = W1 + sp * 128 * 128;
    const float* w2 = W2 + sp * 128;

    s_desc[t] = desc[i * 128 + t];
    __syncthreads();

    // h0[t] = tanh(w0[t,:] . desc + b0[t])
    float acc = b0[sp * 128 + t];
    {
        const float* row = w0 + t * 128;
        #pragma unroll 8
        for (int d = 0; d < 128; ++d) acc += row[d] * s_desc[d];
    }
    const float h0 = tanhf(acc);
    s_h0[t] = h0;
    __syncthreads();

    // h1[t] = tanh(w1[t,:] . h0 + b1[t])
    acc = b1[sp * 128 + t];
    {
        const float* row = w1 + t * 128;
        #pragma unroll 8
        for (int d = 0; d < 128; ++d) acc += row[d] * s_h0[d];
    }
    const float h1 = tanhf(acc);

    // energy partial + d1
    const float w2t = w2[t];
    float ep = w2t * h1;
    #pragma unroll
    for (int o = 32; o > 0; o >>= 1) ep += __shfl_down(ep, o, 64);
    if ((t & 63) == 0) s_red[t >> 6] = ep;

    const float d1 = (1.f - h1 * h1) * w2t;
    s_d1[t] = d1;
    __syncthreads();
    if (t == 0) E[i] = s_red[0] + s_red[1] + b2[sp];

    // dh0[t] = sum_k w1[k,t] * d1[k]  (coalesced across t)
    acc = 0.f;
    #pragma unroll 8
    for (int k = 0; k < 128; ++k) acc += w1[k * 128 + t] * s_d1[k];
    const float d0 = (1.f - h0 * h0) * acc;
    s_d0[t] = d0;
    __syncthreads();

    // G[i,t] = sum_j w0[j,t] * d0[j]  (coalesced across t)
    acc = 0.f;
    #pragma unroll 8
    for (int j = 0; j < 128; ++j) acc += w0[j * 128 + t] * s_d0[j];
    G[i * 128 + t] = acc;
}

// ---------------- Kernel 2: forces partials (the 402 MB stream) ----------------
// Block: 256 threads = 4 waves. Each wave covers 4 consecutive k's (two 1KB
// contiguous clauses per iteration -> 2KB/wave/iter in flight). Block covers
// 16 k's over a 32-atom chunk. grid = 96 k-groups * 16 chunks = 1536 blocks.
// LDS 16KB -> 8 blocks/CU (wave-slot limited), 32 waves/CU.
__global__ __launch_bounds__(256) void forces_kernel(
    const float* __restrict__ CG,      // [N, NK, D]
    const float* __restrict__ G,       // [N, D]
    float* __restrict__ partial)       // [NCHUNK, NK]
{
    const int kg   = blockIdx.x % 96;
    const int ic   = blockIdx.x / 96;
    const int t    = threadIdx.x;
    const int wave = t >> 6;
    const int lane = t & 63;

    __shared__ float s_G[CHUNK * 128];  // 16 KB

    const int i0 = ic * CHUNK;
    {   // cooperative G-chunk load: 4096 floats, float4-vectorized
        const float4* Gv  = (const float4*)(G + (size_t)i0 * 128);
        float4*       sGv = (float4*)s_G;
        #pragma unroll
        for (int r = 0; r < 4; ++r) sGv[r * 256 + t] = Gv[r * 256 + t];
    }
    __syncthreads();

    const int k0   = kg * 16 + wave * 4;  // wave covers k0..k0+3
    const int half = lane >> 5;           // lanes 0-31 -> k0/k0+2, 32-63 -> k0+1/k0+3
    const int l5   = lane & 31;
    const int off  = half * 128 + l5 * 4;

    const float* cgbase = CG + (size_t)i0 * NK * DD + (size_t)k0 * DD + off;
    float acc0 = 0.f, acc1 = 0.f;
    #pragma unroll 4
    for (int i = 0; i < CHUNK; ++i) {
        const float* p = cgbase + (size_t)i * (NK * DD);
        const float4 cg0 = *(const float4*)(p);          // k0 + half
        const float4 cg1 = *(const float4*)(p + 256);    // k0 + 2 + half
        const float4 g   = *(const float4*)(s_G + i * 128 + l5 * 4);
        acc0 += cg0.x * g.x + cg0.y * g.y + cg0.z * g.z + cg0.w * g.w;
        acc1 += cg1.x * g.x + cg1.y * g.y + cg1.z * g.z + cg1.w * g.w;
    }
    // reduce within each 32-lane half (xor offsets < 32 stay in-half)
    #pragma unroll
    for (int o = 16; o > 0; o >>= 1) {
        acc0 += __shfl_xor(acc0, o, 64);
        acc1 += __shfl_xor(acc1, o, 64);
    }
    if (l5 == 0) {
        partial[ic * NK + k0 + half]     = acc0;
        partial[ic * NK + k0 + 2 + half] = acc1;
    }
}

// ---------------- Kernel 3: finalize (forces reduce, stress, energy sum) --------
__global__ __launch_bounds__(256) void finalize_kernel(
    const float* __restrict__ partial, // [NCHUNK, NK]
    const float* __restrict__ E,       // [N]
    const float* __restrict__ SG,      // [N,6,D]
    const float* __restrict__ G,       // [N,D]
    const float* __restrict__ volume,  // [1]
    float* __restrict__ out)           // [1543]
{
    const int b = blockIdx.x;
    const int t = threadIdx.x;
    __shared__ float red[4];

    if (b < 6) {
        // forces: out[1+k] = sum_c partial[c][k]
        const int k = b * 256 + t;
        float f = 0.f;
        #pragma unroll
        for (int c = 0; c < NCHUNK; ++c) f += partial[c * NK + k];
        out[1 + k] = f;
    } else if (b < 12) {
        // stress component s
        const int s = b - 6;
        const int d = t & 127;
        const int ih = t >> 7;
        float acc = 0.f;
        for (int i = ih; i < NATOMS; i += 2)
            acc += SG[((size_t)i * 6 + s) * 128 + d] * G[i * 128 + d];
        #pragma unroll
        for (int o = 32; o > 0; o >>= 1) acc += __shfl_down(acc, o, 64);
        if ((t & 63) == 0) red[t >> 6] = acc;
        __syncthreads();
        if (t == 0) out[1537 + s] = -(red[0] + red[1] + red[2] + red[3]) / volume[0];
    } else {
        // energy sum over 512 atoms
        float acc = E[t] + E[t + 256];
        #pragma unroll
        for (int o = 32; o > 0; o >>= 1) acc += __shfl_down(acc, o, 64);
        if ((t & 63) == 0) red[t >> 6] = acc;
        __syncthreads();
        if (t == 0) out[0] = red[0] + red[1] + red[2] + red[3];
    }
}

extern "C" void kernel_launch(void* const* d_in, const int* in_sizes, int n_in,
                              void* d_out, int out_size, void* d_ws, size_t ws_size,
                              hipStream_t stream) {
    const float* desc    = (const float*)d_in[0];
    const float* CG      = (const float*)d_in[1];
    const float* SG      = (const float*)d_in[2];
    const float* W0      = (const float*)d_in[3];
    const float* b0      = (const float*)d_in[4];
    const float* W1      = (const float*)d_in[5];
    const float* b1      = (const float*)d_in[6];
    const float* W2      = (const float*)d_in[7];
    const float* b2      = (const float*)d_in[8];
    const float* vol     = (const float*)d_in[9];
    const int*   species = (const int*)d_in[10];
    float* out = (float*)d_out;

    float* G       = (float*)d_ws;        // 512*128
    float* E       = G + 512 * 128;       // 512
    float* partial = E + 512;             // NCHUNK*1536

    mlp_grad_kernel<<<NATOMS, 128, 0, stream>>>(desc, W0, b0, W1, b1, W2, b2, species, G, E);
    forces_kernel<<<96 * NCHUNK, 256, 0, stream>>>(CG, G, partial);
    finalize_kernel<<<13, 256, 0, stream>>>(partial, E, SG, G, vol, out);
}

// Round 4
// 524.549 us; speedup vs baseline: 1.2622x; 1.2622x over previous
//
#include <hip/hip_runtime.h>
#include <hip/hip_bf16.h>

#define DD 128
#define HH 128
#define NATOMS 512
#define NK 1536   // 3*N
#define CHUNK 32  // atoms per forces block
#define NCHUNK (NATOMS / CHUNK)  // 16

typedef float floatx4 __attribute__((ext_vector_type(4)));  // native vec for nontemporal builtins

// ---------------- Kernel 1: per-atom MLP fwd + input grad + stress partials ------
// 256 threads per atom: each 128-dot is split across 2 threads (64 MACs each),
// combined via LDS. Halves the gather-instruction count of the row-major forward
// reads and doubles occupancy (8 waves/CU) vs the 128-thread version.
__global__ __launch_bounds__(256) void mlp_grad_kernel(
    const float* __restrict__ desc,    // [N,D]
    const float* __restrict__ SG,      // [N,6,D]
    const float* __restrict__ W0,      // [S,H,D]
    const float* __restrict__ b0,      // [S,H]
    const float* __restrict__ W1,      // [S,H,H]
    const float* __restrict__ b1,      // [S,H]
    const float* __restrict__ W2,      // [S,1,H]
    const float* __restrict__ b2,      // [S,1]
    const int*   __restrict__ species, // [N]
    float* __restrict__ G,             // ws [N,D]
    float* __restrict__ E,             // ws [N]
    float* __restrict__ SP)            // ws [N,6] stress partials
{
    const int i    = blockIdx.x;
    const int t    = threadIdx.x;
    const int half = t >> 7;      // 0/1: which 64-wide slice of the dot
    const int r    = t & 127;     // output row

    __shared__ float s_desc[128];
    __shared__ float s_h0[128];
    __shared__ float s_d1[128];
    __shared__ float s_d0[128];
    __shared__ float s_g[128];
    __shared__ float s_ep[128];
    __shared__ float s_part[256];

    const int sp = species[i];
    const float* w0 = W0 + sp * 128 * 128;
    const float* w1 = W1 + sp * 128 * 128;

    if (t < 128) s_desc[t] = desc[i * 128 + t];
    __syncthreads();

    // ---- layer 0 forward: h0[r] = tanh(w0[r,:].desc + b0[r]) ----
    {
        const float* row = w0 + r * 128 + half * 64;
        const float* dv  = s_desc + half * 64;
        float acc = 0.f;
        #pragma unroll 8
        for (int d = 0; d < 64; ++d) acc += row[d] * dv[d];
        s_part[t] = acc;
    }
    __syncthreads();
    if (t < 128) s_h0[r] = tanhf(s_part[r] + s_part[r + 128] + b0[sp * 128 + r]);
    __syncthreads();

    // ---- layer 1 forward: h1[r] = tanh(w1[r,:].h0 + b1[r]) ----
    {
        const float* row = w1 + r * 128 + half * 64;
        const float* hv  = s_h0 + half * 64;
        float acc = 0.f;
        #pragma unroll 8
        for (int d = 0; d < 64; ++d) acc += row[d] * hv[d];
        s_part[t] = acc;
    }
    __syncthreads();
    if (t < 128) {
        const float h1  = tanhf(s_part[r] + s_part[r + 128] + b1[sp * 128 + r]);
        const float w2r = W2[sp * 128 + r];
        s_ep[r] = w2r * h1;
        s_d1[r] = (1.f - h1 * h1) * w2r;
    }
    __syncthreads();

    // ---- energy reduce (wave 0) runs alongside backward layer 1 ----
    if (t < 64) {
        float v = s_ep[t] + s_ep[t + 64];
        #pragma unroll
        for (int o = 32; o > 0; o >>= 1) v += __shfl_down(v, o, 64);
        if (t == 0) E[i] = v + b2[sp];
    }

    // ---- backward layer 1: d0[r] = (1-h0^2) * sum_k w1[k,r]*d1[k] (coalesced) ----
    {
        float acc = 0.f;
        const int kk0 = half * 64;
        #pragma unroll 8
        for (int k = 0; k < 64; ++k) acc += w1[(kk0 + k) * 128 + r] * s_d1[kk0 + k];
        s_part[t] = acc;
    }
    __syncthreads();
    if (t < 128) {
        const float h0 = s_h0[r];
        s_d0[r] = (1.f - h0 * h0) * (s_part[r] + s_part[r + 128]);
    }
    __syncthreads();

    // ---- backward layer 0: G[r] = sum_j w0[j,r]*d0[j] (coalesced) ----
    {
        float acc = 0.f;
        const int jj0 = half * 64;
        #pragma unroll 8
        for (int j = 0; j < 64; ++j) acc += w0[(jj0 + j) * 128 + r] * s_d0[jj0 + j];
        s_part[t] = acc;
    }
    __syncthreads();
    if (t < 128) {
        const float g = s_part[r] + s_part[r + 128];
        G[i * 128 + r] = g;
        s_g[r] = g;
    }
    __syncthreads();

    // ---- stress partials: SP[i,s] = SG[i,s,:].g  (6 comps x 32 lanes) ----
    if (t < 192) {
        const int s  = t >> 5;
        const int l5 = t & 31;
        const float* sg = SG + ((size_t)i * 6 + s) * 128;
        float acc = 0.f;
        #pragma unroll
        for (int m = 0; m < 4; ++m) acc += sg[l5 + 32 * m] * s_g[l5 + 32 * m];
        #pragma unroll
        for (int o = 16; o > 0; o >>= 1) acc += __shfl_xor(acc, o, 64);
        if (l5 == 0) SP[i * 6 + s] = acc;
    }
}

// ---------------- Kernel 2: forces partials (the 402 MB stream) ----------------
// Wave covers 4 consecutive k's; two contiguous 1KB clauses per iteration.
// Nontemporal loads: CG is streamed exactly once — keep it out of L2.
__global__ __launch_bounds__(256) void forces_kernel(
    const float* __restrict__ CG,      // [N, NK, D]
    const float* __restrict__ G,       // [N, D]
    float* __restrict__ partial)       // [NCHUNK, NK]
{
    const int kg   = blockIdx.x % 96;
    const int ic   = blockIdx.x / 96;
    const int t    = threadIdx.x;
    const int wave = t >> 6;
    const int lane = t & 63;

    __shared__ float s_G[CHUNK * 128];  // 16 KB

    const int i0 = ic * CHUNK;
    {
        const float4* Gv  = (const float4*)(G + (size_t)i0 * 128);
        float4*       sGv = (float4*)s_G;
        #pragma unroll
        for (int r = 0; r < 4; ++r) sGv[r * 256 + t] = Gv[r * 256 + t];
    }
    __syncthreads();

    const int k0    = kg * 16 + wave * 4;
    const int halfw = lane >> 5;
    const int l5    = lane & 31;
    const int off   = halfw * 128 + l5 * 4;

    const float* cgbase = CG + (size_t)i0 * NK * DD + (size_t)k0 * DD + off;
    float acc0 = 0.f, acc1 = 0.f;
    #pragma unroll 4
    for (int i = 0; i < CHUNK; ++i) {
        const float* p = cgbase + (size_t)i * (NK * DD);
        const floatx4 cg0 = __builtin_nontemporal_load((const floatx4*)p);
        const floatx4 cg1 = __builtin_nontemporal_load((const floatx4*)(p + 256));
        const floatx4 g   = *(const floatx4*)(s_G + i * 128 + l5 * 4);
        acc0 += cg0.x * g.x + cg0.y * g.y + cg0.z * g.z + cg0.w * g.w;
        acc1 += cg1.x * g.x + cg1.y * g.y + cg1.z * g.z + cg1.w * g.w;
    }
    #pragma unroll
    for (int o = 16; o > 0; o >>= 1) {
        acc0 += __shfl_xor(acc0, o, 64);
        acc1 += __shfl_xor(acc1, o, 64);
    }
    if (l5 == 0) {
        partial[ic * NK + k0 + halfw]     = acc0;
        partial[ic * NK + k0 + 2 + halfw] = acc1;
    }
}

// ---------------- Kernel 3: finalize ----------------
__global__ __launch_bounds__(256) void finalize_kernel(
    const float* __restrict__ partial, // [NCHUNK, NK]
    const float* __restrict__ E,       // [N]
    const float* __restrict__ SP,      // [N,6]
    const float* __restrict__ volume,  // [1]
    float* __restrict__ out)           // [1543]
{
    const int b = blockIdx.x;
    const int t = threadIdx.x;
    __shared__ float red[4];

    if (b < 6) {
        // forces: out[1+k] = sum_c partial[c][k]
        const int k = b * 256 + t;
        float f = 0.f;
        #pragma unroll
        for (int c = 0; c < NCHUNK; ++c) f += partial[c * NK + k];
        out[1 + k] = f;
    } else if (b < 12) {
        // stress component s: sum SP[i,s] over i
        const int s = b - 6;
        float acc = SP[t * 6 + s] + SP[(t + 256) * 6 + s];
        #pragma unroll
        for (int o = 32; o > 0; o >>= 1) acc += __shfl_down(acc, o, 64);
        if ((t & 63) == 0) red[t >> 6] = acc;
        __syncthreads();
        if (t == 0) out[1537 + s] = -(red[0] + red[1] + red[2] + red[3]) / volume[0];
    } else {
        // energy sum over 512 atoms
        float acc = E[t] + E[t + 256];
        #pragma unroll
        for (int o = 32; o > 0; o >>= 1) acc += __shfl_down(acc, o, 64);
        if ((t & 63) == 0) red[t >> 6] = acc;
        __syncthreads();
        if (t == 0) out[0] = red[0] + red[1] + red[2] + red[3];
    }
}

extern "C" void kernel_launch(void* const* d_in, const int* in_sizes, int n_in,
                              void* d_out, int out_size, void* d_ws, size_t ws_size,
                              hipStream_t stream) {
    const float* desc    = (const float*)d_in[0];
    const float* CG      = (const float*)d_in[1];
    const float* SG      = (const float*)d_in[2];
    const float* W0      = (const float*)d_in[3];
    const float* b0      = (const float*)d_in[4];
    const float* W1      = (const float*)d_in[5];
    const float* b1      = (const float*)d_in[6];
    const float* W2      = (const float*)d_in[7];
    const float* b2      = (const float*)d_in[8];
    const float* vol     = (const float*)d_in[9];
    const int*   species = (const int*)d_in[10];
    float* out = (float*)d_out;

    float* G       = (float*)d_ws;            // 512*128
    float* E       = G + 512 * 128;           // 512
    float* partial = E + 512;                 // NCHUNK*1536
    float* SP      = partial + NCHUNK * NK;   // 512*6

    mlp_grad_kernel<<<NATOMS, 256, 0, stream>>>(desc, SG, W0, b0, W1, b1, W2, b2,
                                                species, G, E, SP);
    forces_kernel<<<96 * NCHUNK, 256, 0, stream>>>(CG, G, partial);
    finalize_kernel<<<13, 256, 0, stream>>>(partial, E, SP, vol, out);
}